// Round 1
// baseline (395.508 us; speedup 1.0000x reference)
//
#include <hip/hip_runtime.h>

#define SS 2048
#define DD 1024
#define HH 16
#define DKK 64
#define MM 4096
#define NN 1024
#define KK 1024

typedef __attribute__((ext_vector_type(8))) short bf16x8;
typedef __attribute__((ext_vector_type(4))) float f32x4;
typedef __attribute__((ext_vector_type(4))) float float4_t;
typedef __attribute__((ext_vector_type(4))) short short4_t;

__device__ __forceinline__ short f2bf(float f) {
    union { float f; unsigned u; } x; x.f = f;
    unsigned r = x.u + 0x7fffu + ((x.u >> 16) & 1u);
    return (short)(r >> 16);
}

__device__ __forceinline__ f32x4 mfma16(bf16x8 a, bf16x8 b, f32x4 c) {
    return __builtin_amdgcn_mfma_f32_16x16x32_bf16(a, b, c, 0, 0, 0);
}

// ---- shared GEMM main loop: acc(128x128 tile) += A[m0+.][k] * W[n0+.][k]  (C = A * W^T) ----
__device__ __forceinline__ void gemm_main(const float* __restrict__ A,
                                          const float* __restrict__ W,
                                          int m0, int n0,
                                          short* As, short* Bs,
                                          f32x4 acc[4][4]) {
    const int tid = threadIdx.x;
    const int lane = tid & 63;
    const int w = tid >> 6;
    const int wr = w >> 1, wc = w & 1;
    const int lr = lane & 15, lg = lane >> 4;

    for (int kt = 0; kt < KK / 32; ++kt) {
        const int k0 = kt * 32;
        // stage: 1024 chunks (128 rows x 8 float4) per operand, fp32 -> bf16 (RNE)
#pragma unroll
        for (int j = 0; j < 4; ++j) {
            const int c = j * 256 + tid;
            const int row = c >> 3, cc = c & 7;
            float4_t va = *(const float4_t*)(A + (size_t)(m0 + row) * KK + k0 + cc * 4);
            float4_t vb = *(const float4_t*)(W + (size_t)(n0 + row) * KK + k0 + cc * 4);
            short4_t sa, sb;
#pragma unroll
            for (int e = 0; e < 4; ++e) { sa[e] = f2bf(va[e]); sb[e] = f2bf(vb[e]); }
            // padded LDS row: 40 shorts (80 B) -> 2-way-max bank pattern on b128 reads
            *(short4_t*)(As + row * 40 + cc * 4) = sa;
            *(short4_t*)(Bs + row * 40 + cc * 4) = sb;
        }
        __syncthreads();
        bf16x8 af[4], bfr[4];
#pragma unroll
        for (int i = 0; i < 4; ++i) {
            af[i]  = *(const bf16x8*)(As + (wr * 64 + i * 16 + lr) * 40 + lg * 8);
            bfr[i] = *(const bf16x8*)(Bs + (wc * 64 + i * 16 + lr) * 40 + lg * 8);
        }
#pragma unroll
        for (int mi = 0; mi < 4; ++mi)
#pragma unroll
            for (int ni = 0; ni < 4; ++ni)
                acc[mi][ni] = mfma16(af[mi], bfr[ni], acc[mi][ni]);
        __syncthreads();
    }
}

// ---- QKV projections: z=0 -> Q (scaled by 0.125, head-major), z=1 -> K (head-major), z=2 -> V^T ----
__global__ __launch_bounds__(256, 2)
void qkv_gemm(const float* __restrict__ Xq, const float* __restrict__ Xk, const float* __restrict__ Xv,
              const float* __restrict__ Wq, const float* __restrict__ Wk, const float* __restrict__ Wv,
              const float* __restrict__ bq, const float* __restrict__ bk, const float* __restrict__ bv,
              short* __restrict__ Qo, short* __restrict__ Ko, short* __restrict__ Vto) {
    __shared__ __align__(16) short As[128 * 40];
    __shared__ __align__(16) short Bs[128 * 40];
    const int z = blockIdx.z;
    const float* A    = (z == 0) ? Xq : (z == 1) ? Xk : Xv;
    const float* W    = (z == 0) ? Wq : (z == 1) ? Wk : Wv;
    const float* bias = (z == 0) ? bq : (z == 1) ? bk : bv;
    const float scale = (z == 0) ? 0.125f : 1.0f;
    const int m0 = blockIdx.x * 128, n0 = blockIdx.y * 128;

    f32x4 zero = {0.f, 0.f, 0.f, 0.f};
    f32x4 acc[4][4];
#pragma unroll
    for (int i = 0; i < 4; ++i)
#pragma unroll
        for (int j = 0; j < 4; ++j) acc[i][j] = zero;

    gemm_main(A, W, m0, n0, As, Bs, acc);

    const int tid = threadIdx.x;
    const int lane = tid & 63;
    const int w = tid >> 6;
    const int wr = w >> 1, wc = w & 1;
    const int lr = lane & 15, lg = lane >> 4;

#pragma unroll
    for (int mi = 0; mi < 4; ++mi) {
        const int mbase = m0 + wr * 64 + mi * 16 + lg * 4;
#pragma unroll
        for (int ni = 0; ni < 4; ++ni) {
            const int n = n0 + wc * 64 + ni * 16 + lr;
            const float bvv = bias[n];
            const int h = n >> 6, dk = n & 63;
            if (z == 2) {
                // Vt[B][H][DK][S], 4 consecutive s -> packed 8B store
                short4_t pk;
#pragma unroll
                for (int r = 0; r < 4; ++r) pk[r] = f2bf(acc[mi][ni][r] + bvv);
                const int b = mbase >> 11, s = mbase & 2047;
                *(short4_t*)(Vto + ((size_t)((b * HH + h) * DKK + dk) << 11) + s) = pk;
            } else {
                short* dst = (z == 0) ? Qo : Ko;
#pragma unroll
                for (int r = 0; r < 4; ++r) {
                    const int m = mbase + r;
                    const int b = m >> 11, s = m & 2047;
                    dst[((size_t)((b * HH + h) * SS + s) << 6) + dk] =
                        f2bf((acc[mi][ni][r] + bvv) * scale);
                }
            }
        }
    }
}

// ---- output projection: out = ctx * Wo^T + bo (fp32 out) ----
__global__ __launch_bounds__(256, 2)
void out_gemm(const float* __restrict__ ctx, const float* __restrict__ Wo,
              const float* __restrict__ bo, float* __restrict__ out) {
    __shared__ __align__(16) short As[128 * 40];
    __shared__ __align__(16) short Bs[128 * 40];
    const int m0 = blockIdx.x * 128, n0 = blockIdx.y * 128;

    f32x4 zero = {0.f, 0.f, 0.f, 0.f};
    f32x4 acc[4][4];
#pragma unroll
    for (int i = 0; i < 4; ++i)
#pragma unroll
        for (int j = 0; j < 4; ++j) acc[i][j] = zero;

    gemm_main(ctx, Wo, m0, n0, As, Bs, acc);

    const int tid = threadIdx.x;
    const int lane = tid & 63;
    const int w = tid >> 6;
    const int wr = w >> 1, wc = w & 1;
    const int lr = lane & 15, lg = lane >> 4;

#pragma unroll
    for (int mi = 0; mi < 4; ++mi)
#pragma unroll
        for (int ni = 0; ni < 4; ++ni) {
            const int n = n0 + wc * 64 + ni * 16 + lr;
            const float bvv = bo[n];
#pragma unroll
            for (int r = 0; r < 4; ++r) {
                const int m = m0 + wr * 64 + mi * 16 + lg * 4 + r;
                out[(size_t)m * NN + n] = acc[mi][ni][r] + bvv;
            }
        }
}

// ---- flash attention: Q,K head-major bf16 (Q pre-scaled), Vt = V^T bf16, ctx fp32 [B][S][D] ----
__global__ __launch_bounds__(256, 3)
void attn_kernel(const short* __restrict__ Qg, const short* __restrict__ Kg,
                 const short* __restrict__ Vtg, const int* __restrict__ mask,
                 float* __restrict__ ctx) {
    __shared__ __align__(16) short Ks[64 * 64];   // [key][d], XOR-swizzled
    __shared__ __align__(16) short Vs[64 * 64];   // [d][key], XOR-swizzled
    __shared__ __align__(16) short Ps[4][16][72]; // per-wave P, padded rows

    const int tid = threadIdx.x, w = tid >> 6, lane = tid & 63;
    const int lr = lane & 15, lg = lane >> 4;
    const int bh = blockIdx.y;
    const int b = bh >> 4, h = bh & 15;
    const int q0 = blockIdx.x * 64 + w * 16;  // this wave's 16 q-rows

    const short* Qh  = Qg  + (size_t)bh * SS * DKK;
    const short* Kh  = Kg  + (size_t)bh * SS * DKK;
    const short* Vth = Vtg + (size_t)bh * DKK * SS;
    const int* mrow = mask + b * SS;

    // Q fragments held in registers for the whole block
    bf16x8 qf0 = *(const bf16x8*)(Qh + (q0 + lr) * 64 + lg * 8);
    bf16x8 qf1 = *(const bf16x8*)(Qh + (q0 + lr) * 64 + 32 + lg * 8);

    float mrun[4], lrun[4];
    f32x4 zero = {0.f, 0.f, 0.f, 0.f};
    f32x4 octx[4];
#pragma unroll
    for (int r = 0; r < 4; ++r) { mrun[r] = -1e30f; lrun[r] = 0.f; octx[r] = zero; }

    for (int it = 0; it < SS / 64; ++it) {
        const int key0 = it * 64;
        // stage K tile [64 keys][64 d] and Vt tile [64 d][64 keys] with XOR swizzle
#pragma unroll
        for (int j = 0; j < 2; ++j) {
            const int c = j * 256 + tid;       // chunk 0..511 (16B chunks)
            const int row = c >> 3;
            uint4 kv = *(const uint4*)((const char*)(Kh + key0 * 64) + c * 16);
            uint4 vv = *(const uint4*)((const char*)Vth + (size_t)row * (SS * 2) + key0 * 2 + (c & 7) * 16);
            const int dst = (c * 16) ^ ((row & 7) << 4);
            *(uint4*)((char*)Ks + dst) = kv;
            *(uint4*)((char*)Vs + dst) = vv;
        }
        __syncthreads();

        // QK^T : scores for 16 q x 64 keys (4 key-blocks), Q pre-scaled by 1/8
        f32x4 sc[4];
#pragma unroll
        for (int kb = 0; kb < 4; ++kb) {
            const int row = kb * 16 + lr;
            const char* base = (const char*)Ks + row * 128;
            const int sw = (row & 7) << 4;
            bf16x8 k0 = *(const bf16x8*)(base + ((lg * 16) ^ sw));
            bf16x8 k1 = *(const bf16x8*)(base + ((64 + lg * 16) ^ sw));
            f32x4 zz = zero;
            zz = mfma16(qf0, k0, zz);
            zz = mfma16(qf1, k1, zz);
            sc[kb] = zz;
        }
        // mask (B,1,1,S): key-wise
#pragma unroll
        for (int kb = 0; kb < 4; ++kb) {
            if (mrow[key0 + kb * 16 + lr] == 0) {
                sc[kb][0] = -1e9f; sc[kb][1] = -1e9f; sc[kb][2] = -1e9f; sc[kb][3] = -1e9f;
            }
        }
        // online softmax (rows r, per 16-lane group)
        float al[4];
#pragma unroll
        for (int r = 0; r < 4; ++r) {
            float tm = fmaxf(fmaxf(sc[0][r], sc[1][r]), fmaxf(sc[2][r], sc[3][r]));
#pragma unroll
            for (int off = 1; off < 16; off <<= 1) tm = fmaxf(tm, __shfl_xor(tm, off));
            const float mnew = fmaxf(mrun[r], tm);
            al[r] = __expf(mrun[r] - mnew);
            float rs = 0.f;
#pragma unroll
            for (int kb = 0; kb < 4; ++kb) {
                const float pv = __expf(sc[kb][r] - mnew);
                sc[kb][r] = pv;
                rs += pv;
            }
#pragma unroll
            for (int off = 1; off < 16; off <<= 1) rs += __shfl_xor(rs, off);
            lrun[r] = lrun[r] * al[r] + rs;
            mrun[r] = mnew;
        }
#pragma unroll
        for (int db = 0; db < 4; ++db)
#pragma unroll
            for (int r = 0; r < 4; ++r) octx[db][r] *= al[r];

        // P -> per-wave LDS (bf16), then PV
#pragma unroll
        for (int kb = 0; kb < 4; ++kb)
#pragma unroll
            for (int r = 0; r < 4; ++r)
                Ps[w][lg * 4 + r][kb * 16 + lr] = f2bf(sc[kb][r]);

        bf16x8 pa0 = *(const bf16x8*)(&Ps[w][lr][0]  + lg * 8);
        bf16x8 pa1 = *(const bf16x8*)(&Ps[w][lr][32] + lg * 8);
#pragma unroll
        for (int db = 0; db < 4; ++db) {
            const int row = db * 16 + lr;
            const char* base = (const char*)Vs + row * 128;
            const int sw = (row & 7) << 4;
            bf16x8 v0 = *(const bf16x8*)(base + ((lg * 16) ^ sw));
            bf16x8 v1 = *(const bf16x8*)(base + ((64 + lg * 16) ^ sw));
            octx[db] = mfma16(pa0, v0, octx[db]);
            octx[db] = mfma16(pa1, v1, octx[db]);
        }
        __syncthreads();
    }

    // epilogue: ctx[b][s][h*64+d] fp32
#pragma unroll
    for (int r = 0; r < 4; ++r) {
        const float inv = 1.f / lrun[r];
        const int s = q0 + lg * 4 + r;
        float* orow = ctx + ((size_t)(b * SS + s)) * DD + h * 64;
#pragma unroll
        for (int db = 0; db < 4; ++db)
            orow[db * 16 + lr] = octx[db][r] * inv;
    }
}

extern "C" void kernel_launch(void* const* d_in, const int* in_sizes, int n_in,
                              void* d_out, int out_size, void* d_ws, size_t ws_size,
                              hipStream_t stream) {
    const float* preQ = (const float*)d_in[0];
    const float* preK = (const float*)d_in[1];
    const float* preV = (const float*)d_in[2];
    const float* Wq   = (const float*)d_in[3];
    const float* bq   = (const float*)d_in[4];
    const float* Wk   = (const float*)d_in[5];
    const float* bk   = (const float*)d_in[6];
    const float* Wv   = (const float*)d_in[7];
    const float* bv   = (const float*)d_in[8];
    const float* Wo   = (const float*)d_in[9];
    const float* bo   = (const float*)d_in[10];
    const int*   mask = (const int*)d_in[11];
    float* out = (float*)d_out;

    char* ws = (char*)d_ws;
    short* Qw   = (short*)(ws);
    short* Kw   = (short*)(ws + ((size_t)8 << 20));
    short* Vtw  = (short*)(ws + ((size_t)16 << 20));
    float* ctxw = (float*)(ws + ((size_t)24 << 20));

    qkv_gemm<<<dim3(32, 8, 3), 256, 0, stream>>>(preQ, preK, preV, Wq, Wk, Wv,
                                                 bq, bk, bv, Qw, Kw, Vtw);
    attn_kernel<<<dim3(32, 32), 256, 0, stream>>>(Qw, Kw, Vtw, mask, ctxw);
    out_gemm<<<dim3(32, 8), 256, 0, stream>>>(ctxw, Wo, bo, out);
}

// Round 2
// 256.405 us; speedup vs baseline: 1.5425x; 1.5425x over previous
//
#include <hip/hip_runtime.h>

#define SS 2048
#define DD 1024
#define HH 16
#define MM 4096
#define KK 1024

typedef __attribute__((ext_vector_type(8))) short bf16x8;
typedef __attribute__((ext_vector_type(4))) float f32x4;
typedef __attribute__((ext_vector_type(4))) float float4_t;
typedef __attribute__((ext_vector_type(4))) short short4_t;
typedef __attribute__((ext_vector_type(4))) int iv4;

__device__ __forceinline__ short f2bf(float f) {
    union { float f; unsigned u; } x; x.f = f;
    unsigned r = x.u + 0x7fffu + ((x.u >> 16) & 1u);
    return (short)(r >> 16);
}

__device__ __forceinline__ f32x4 mfma16(bf16x8 a, bf16x8 b, f32x4 c) {
    return __builtin_amdgcn_mfma_f32_16x16x32_bf16(a, b, c, 0, 0, 0);
}

__device__ __forceinline__ void gl_lds16(const void* g, void* l) {
    __builtin_amdgcn_global_load_lds(
        (const __attribute__((address_space(1))) void*)g,
        (__attribute__((address_space(3))) void*)l, 16, 0, 0);
}

// ---------------- conversion passes: fp32 -> bf16 ----------------
__global__ __launch_bounds__(256)
void convX(const float* __restrict__ x0, const float* __restrict__ x1,
           const float* __restrict__ x2, short* __restrict__ dst) {
    const float* s = (blockIdx.y == 0) ? x0 : (blockIdx.y == 1) ? x1 : x2;
    const size_t i = ((size_t)blockIdx.x * 256 + threadIdx.x) * 8;
    float4_t a = *(const float4_t*)(s + i);
    float4_t b = *(const float4_t*)(s + i + 4);
    bf16x8 o;
#pragma unroll
    for (int e = 0; e < 4; ++e) { o[e] = f2bf(a[e]); o[4 + e] = f2bf(b[e]); }
    *(bf16x8*)(dst + (size_t)blockIdx.y * MM * KK + i) = o;
}

__global__ __launch_bounds__(256)
void convW(const float* __restrict__ w0, const float* __restrict__ w1,
           const float* __restrict__ w2, const float* __restrict__ w3,
           short* __restrict__ dst) {
    const float* s = (blockIdx.y == 0) ? w0 : (blockIdx.y == 1) ? w1
                   : (blockIdx.y == 2) ? w2 : w3;
    const size_t i = ((size_t)blockIdx.x * 256 + threadIdx.x) * 8;
    float4_t a = *(const float4_t*)(s + i);
    float4_t b = *(const float4_t*)(s + i + 4);
    bf16x8 o;
#pragma unroll
    for (int e = 0; e < 4; ++e) { o[e] = f2bf(a[e]); o[4 + e] = f2bf(b[e]); }
    *(bf16x8*)(dst + (size_t)blockIdx.y * KK * KK + i) = o;
}

// ---------------- m97-style bf16 GEMM core: C += A * W^T ----------------
// A [M][K] bf16, W [N][K] bf16. 128x128 tile, BK=32, gload_lds(16B), 2-phase dbuf.
__device__ __forceinline__ void gemm_loop(const short* __restrict__ A,
                                          const short* __restrict__ Bw,
                                          int m0, int n0,
                                          short* As, short* Bs,  // each 2*4096 shorts
                                          f32x4 acc[4][4]) {
    const int tid = threadIdx.x;
    const int lane = tid & 63, w = tid >> 6;
    const int wr = w >> 1, wc = w & 1;
    const int lr = lane & 15, lg = lane >> 4;

    const int c1 = tid + 256;
    const int r0 = tid >> 2, o0 = (tid & 3) * 8;
    const int r1 = c1 >> 2, o1 = (c1 & 3) * 8;
    const short* ga0 = A + (size_t)(m0 + r0) * KK + o0;
    const short* ga1 = A + (size_t)(m0 + r1) * KK + o1;
    const short* gb0 = Bw + (size_t)(n0 + r0) * KK + o0;
    const short* gb1 = Bw + (size_t)(n0 + r1) * KK + o1;
    char* lA = (char*)As + tid * 16;
    char* lB = (char*)Bs + tid * 16;

#define GSTAGE(buf, kofs)                                  \
    { gl_lds16(ga0 + (kofs), lA + (buf) * 8192);           \
      gl_lds16(ga1 + (kofs), lA + 4096 + (buf) * 8192);    \
      gl_lds16(gb0 + (kofs), lB + (buf) * 8192);           \
      gl_lds16(gb1 + (kofs), lB + 4096 + (buf) * 8192); }

    GSTAGE(0, 0);
    __syncthreads();
    int cur = 0;
    for (int kt = 0; kt < KK / 32; ++kt) {
        if (kt + 1 < KK / 32) GSTAGE(cur ^ 1, (kt + 1) * 32);
        const char* ba = (const char*)As + cur * 8192;
        const char* bb = (const char*)Bs + cur * 8192;
        bf16x8 af[4], bfr[4];
#pragma unroll
        for (int i = 0; i < 4; ++i) {
            af[i]  = *(const bf16x8*)(ba + (wr * 64 + i * 16 + lr) * 64 + lg * 16);
            bfr[i] = *(const bf16x8*)(bb + (wc * 64 + i * 16 + lr) * 64 + lg * 16);
        }
#pragma unroll
        for (int mi = 0; mi < 4; ++mi)
#pragma unroll
            for (int ni = 0; ni < 4; ++ni)
                acc[mi][ni] = mfma16(af[mi], bfr[ni], acc[mi][ni]);
        __syncthreads();
        cur ^= 1;
    }
#undef GSTAGE
}

// ---- QKV projections: z=0 -> Q (scaled, head-major), z=1 -> K (head-major), z=2 -> V^T (slot-permuted) ----
__global__ __launch_bounds__(256, 2)
void qkv_gemm(const short* __restrict__ Xb, const short* __restrict__ Wb,
              const float* __restrict__ bq, const float* __restrict__ bk,
              const float* __restrict__ bv,
              short* __restrict__ Qo, short* __restrict__ Ko, short* __restrict__ Vto) {
    __shared__ __align__(16) short As[2 * 4096];
    __shared__ __align__(16) short Bs[2 * 4096];
    const int z = blockIdx.z;
    const short* A = Xb + (size_t)z * MM * KK;
    const short* W = Wb + (size_t)z * KK * KK;
    const float* bias = (z == 0) ? bq : (z == 1) ? bk : bv;
    const float scale = (z == 0) ? 0.125f : 1.0f;
    const int m0 = blockIdx.x * 128, n0 = blockIdx.y * 128;

    f32x4 zero = {0.f, 0.f, 0.f, 0.f};
    f32x4 acc[4][4];
#pragma unroll
    for (int i = 0; i < 4; ++i)
#pragma unroll
        for (int j = 0; j < 4; ++j) acc[i][j] = zero;

    gemm_loop(A, W, m0, n0, As, Bs, acc);

    const int tid = threadIdx.x;
    const int lane = tid & 63, w = tid >> 6;
    const int wr = w >> 1, wc = w & 1;
    const int lr = lane & 15, lg = lane >> 4;

#pragma unroll
    for (int mi = 0; mi < 4; ++mi) {
        const int mbase = m0 + wr * 64 + mi * 16 + lg * 4;
        const int b = mbase >> 11, s = mbase & 2047;
#pragma unroll
        for (int ni = 0; ni < 4; ++ni) {
            const int n = n0 + wc * 64 + ni * 16 + lr;
            const float bvv = bias[n];
            const int h = n >> 6, dk = n & 63;
            if (z == 2) {
                // Vt[b][h][dk][s'], s' slot-permuted within each 32-block
                short4_t pk;
#pragma unroll
                for (int r = 0; r < 4; ++r) pk[r] = f2bf(acc[mi][ni][r] + bvv);
                const int sp = (s & ~31) | (lg * 8 + (mi & 1) * 4);
                *(short4_t*)(Vto + ((size_t)((b * HH + h) * 64 + dk) << 11) + sp) = pk;
            } else {
                short* dst = (z == 0) ? Qo : Ko;
#pragma unroll
                for (int r = 0; r < 4; ++r)
                    dst[((size_t)((b * HH + h) * SS + (s + r)) << 6) + dk] =
                        f2bf((acc[mi][ni][r] + bvv) * scale);
            }
        }
    }
}

// ---- output projection: out = ctx * Wo^T + bo (fp32) ----
__global__ __launch_bounds__(256, 2)
void out_gemm(const short* __restrict__ ctx, const short* __restrict__ Wo,
              const float* __restrict__ bo, float* __restrict__ out) {
    __shared__ __align__(16) short As[2 * 4096];
    __shared__ __align__(16) short Bs[2 * 4096];
    const int m0 = blockIdx.x * 128, n0 = blockIdx.y * 128;

    f32x4 zero = {0.f, 0.f, 0.f, 0.f};
    f32x4 acc[4][4];
#pragma unroll
    for (int i = 0; i < 4; ++i)
#pragma unroll
        for (int j = 0; j < 4; ++j) acc[i][j] = zero;

    gemm_loop(ctx, Wo, m0, n0, As, Bs, acc);

    const int tid = threadIdx.x;
    const int lane = tid & 63, w = tid >> 6;
    const int wr = w >> 1, wc = w & 1;
    const int lr = lane & 15, lg = lane >> 4;

#pragma unroll
    for (int mi = 0; mi < 4; ++mi)
#pragma unroll
        for (int ni = 0; ni < 4; ++ni) {
            const int n = n0 + wc * 64 + ni * 16 + lr;
            const float bvv = bo[n];
#pragma unroll
            for (int r = 0; r < 4; ++r) {
                const int m = m0 + wr * 64 + mi * 16 + lg * 4 + r;
                out[(size_t)m * KK + n] = acc[mi][ni][r] + bvv;
            }
        }
}

// ---- flash attention, swapped QK^T: P lane-resident, no LDS P roundtrip ----
// Q,K head-major bf16 (Q pre-scaled); Vt[b][h][d][s'] slot-permuted bf16; ctx bf16 [B][S][D]
__global__ __launch_bounds__(256, 2)
void attn_kernel(const short* __restrict__ Qg, const short* __restrict__ Kg,
                 const short* __restrict__ Vtg, const int* __restrict__ mask,
                 short* __restrict__ ctxb) {
    __shared__ __align__(16) short Ks[2][4096];  // [key(64)][d(64)] XOR-swizzled
    __shared__ __align__(16) short Vs[2][4096];  // [d(64)][slot(64)] XOR-swizzled

    const int tid = threadIdx.x, w = tid >> 6, lane = tid & 63;
    const int lr = lane & 15, lg = lane >> 4;
    const int bh = blockIdx.y, b = bh >> 4, h = bh & 15;
    const int q0w = blockIdx.x * 64 + w * 16;  // this wave's 16 q-rows

    const short* Qh = Qg + (size_t)bh * SS * 64;
    const short* Kh = Kg + (size_t)bh * SS * 64;
    const short* Vh = Vtg + (size_t)bh * 64 * SS;
    const int* mrow = mask + b * SS;

    // Q B-fragments (q = q0w + lr), held all loop
    bf16x8 qf0 = *(const bf16x8*)(Qh + (q0w + lr) * 64 + lg * 8);
    bf16x8 qf1 = *(const bf16x8*)(Qh + (q0w + lr) * 64 + 32 + lg * 8);

    f32x4 zero = {0.f, 0.f, 0.f, 0.f};
    f32x4 octx[4];
#pragma unroll
    for (int dt = 0; dt < 4; ++dt) octx[dt] = zero;
    float mrun = -1e30f, lrun = 0.f;  // for q = q0w + lr

    // staging: 512 16B-chunks per tile; thread t handles chunks t and t+256
    const int c1 = tid + 256;
    const int kr0 = tid >> 3, kc0 = ((tid & 7) ^ (kr0 & 7)) * 8;
    const int kr1 = c1 >> 3, kc1 = ((c1 & 7) ^ (kr1 & 7)) * 8;
    const short* gk0 = Kh + kr0 * 64 + kc0;
    const short* gk1 = Kh + kr1 * 64 + kc1;
    const short* gv0 = Vh + (size_t)kr0 * SS + kc0;
    const short* gv1 = Vh + (size_t)kr1 * SS + kc1;
    char* lK = (char*)Ks + tid * 16;
    char* lV = (char*)Vs + tid * 16;

#define ASTAGE(buf, key0)                                    \
    { gl_lds16(gk0 + (key0) * 64, lK + (buf) * 8192);        \
      gl_lds16(gk1 + (key0) * 64, lK + 4096 + (buf) * 8192); \
      gl_lds16(gv0 + (key0), lV + (buf) * 8192);             \
      gl_lds16(gv1 + (key0), lV + 4096 + (buf) * 8192); }

    ASTAGE(0, 0);
    __syncthreads();
    int cur = 0;

    for (int it = 0; it < SS / 64; ++it) {
        const int key0 = it * 64;
        if (it + 1 < SS / 64) ASTAGE(cur ^ 1, key0 + 64);

        const char* bK = (const char*)Ks + cur * 8192;
        const char* bV = (const char*)Vs + cur * 8192;

        // S^T = K * Q^T : sc[kb][r] = S[key=kb*16+lg*4+r][q=lr]
        f32x4 sc[4];
#pragma unroll
        for (int kb = 0; kb < 4; ++kb) {
            const int row = kb * 16 + lr;
            const char* rb = bK + row * 128;
            const int sw = row & 7;
            bf16x8 k0 = *(const bf16x8*)(rb + ((lg ^ sw) * 16));
            bf16x8 k1 = *(const bf16x8*)(rb + (((4 + lg) ^ sw) * 16));
            f32x4 s = zero;
            s = mfma16(k0, qf0, s);
            s = mfma16(k1, qf1, s);
            sc[kb] = s;
        }
        // mask (key-wise)
#pragma unroll
        for (int kb = 0; kb < 4; ++kb) {
            iv4 mv = *(const iv4*)(mrow + key0 + kb * 16 + lg * 4);
#pragma unroll
            for (int r = 0; r < 4; ++r)
                if (mv[r] == 0) sc[kb][r] = -1e9f;
        }
        // online softmax for q=lr: in-lane over 16 keys + 2 shuffles across lg
        float tm = -1e30f;
#pragma unroll
        for (int kb = 0; kb < 4; ++kb)
#pragma unroll
            for (int r = 0; r < 4; ++r) tm = fmaxf(tm, sc[kb][r]);
        tm = fmaxf(tm, __shfl_xor(tm, 16));
        tm = fmaxf(tm, __shfl_xor(tm, 32));
        const float mnew = fmaxf(mrun, tm);
        float rs = 0.f;
#pragma unroll
        for (int kb = 0; kb < 4; ++kb)
#pragma unroll
            for (int r = 0; r < 4; ++r) {
                const float p = __expf(sc[kb][r] - mnew);
                sc[kb][r] = p;
                rs += p;
            }
        rs += __shfl_xor(rs, 16);
        rs += __shfl_xor(rs, 32);
        const float alpha = __expf(mrun - mnew);
        lrun = lrun * alpha + rs;
        mrun = mnew;

        // rescale octx (rows are q = lg*4+r -> fetch alpha from lane q)
        float aq[4];
#pragma unroll
        for (int r = 0; r < 4; ++r) aq[r] = __shfl(alpha, lg * 4 + r);
#pragma unroll
        for (int dt = 0; dt < 4; ++dt)
#pragma unroll
            for (int r = 0; r < 4; ++r) octx[dt][r] *= aq[r];

        // pack P into PV A-fragments (key order matches V slot permutation)
        bf16x8 pa01, pa23;
#pragma unroll
        for (int j = 0; j < 4; ++j) {
            pa01[j] = f2bf(sc[0][j]); pa01[4 + j] = f2bf(sc[1][j]);
            pa23[j] = f2bf(sc[2][j]); pa23[4 + j] = f2bf(sc[3][j]);
        }
        // PV: octx[q=lg*4+r][d=dt*16+lr]
#pragma unroll
        for (int dt = 0; dt < 4; ++dt) {
            const int row = dt * 16 + lr;
            const char* rb = bV + row * 128;
            const int sw = row & 7;
            bf16x8 v0 = *(const bf16x8*)(rb + ((lg ^ sw) * 16));
            bf16x8 v1 = *(const bf16x8*)(rb + (((4 + lg) ^ sw) * 16));
            octx[dt] = mfma16(pa01, v0, octx[dt]);
            octx[dt] = mfma16(pa23, v1, octx[dt]);
        }
        __syncthreads();
        cur ^= 1;
    }
#undef ASTAGE

    // epilogue: ctx[b][s=q0w+lg*4+r][h*64 + dt*16 + lr] (bf16)
    float li[4];
#pragma unroll
    for (int r = 0; r < 4; ++r) li[r] = 1.f / __shfl(lrun, lg * 4 + r);
#pragma unroll
    for (int dt = 0; dt < 4; ++dt)
#pragma unroll
        for (int r = 0; r < 4; ++r)
            ctxb[(size_t)(b * SS + q0w + lg * 4 + r) * DD + h * 64 + dt * 16 + lr] =
                f2bf(octx[dt][r] * li[r]);
}

extern "C" void kernel_launch(void* const* d_in, const int* in_sizes, int n_in,
                              void* d_out, int out_size, void* d_ws, size_t ws_size,
                              hipStream_t stream) {
    const float* preQ = (const float*)d_in[0];
    const float* preK = (const float*)d_in[1];
    const float* preV = (const float*)d_in[2];
    const float* Wq   = (const float*)d_in[3];
    const float* bq   = (const float*)d_in[4];
    const float* Wk   = (const float*)d_in[5];
    const float* bk   = (const float*)d_in[6];
    const float* Wv   = (const float*)d_in[7];
    const float* bv   = (const float*)d_in[8];
    const float* Wo   = (const float*)d_in[9];
    const float* bo   = (const float*)d_in[10];
    const int*   mask = (const int*)d_in[11];
    float* out = (float*)d_out;

    char* ws = (char*)d_ws;
    short* Xb  = (short*)(ws);                           // 3 * 4M * 2B = 24 MB
    short* Wb  = (short*)(ws + (size_t)25165824);        // 4 * 1M * 2B = 8 MB
    short* Qw  = (short*)(ws + (size_t)33554432);        // 8 MB
    short* Kw  = (short*)(ws + (size_t)41943040);        // 8 MB
    short* Vtw = (short*)(ws + (size_t)50331648);        // 8 MB
    short* Ctx = (short*)(ws + (size_t)58720256);        // 8 MB

    convX<<<dim3(2048, 3), 256, 0, stream>>>(preQ, preK, preV, Xb);
    convW<<<dim3(512, 4), 256, 0, stream>>>(Wq, Wk, Wv, Wo, Wb);
    qkv_gemm<<<dim3(32, 8, 3), 256, 0, stream>>>(Xb, Wb, bq, bk, bv, Qw, Kw, Vtw);
    attn_kernel<<<dim3(32, 32), 256, 0, stream>>>(Qw, Kw, Vtw, mask, Ctx);
    out_gemm<<<dim3(32, 8), 256, 0, stream>>>(Ctx, Wb + (size_t)3 * KK * KK, bo, out);
}

// Round 3
// 240.512 us; speedup vs baseline: 1.6444x; 1.0661x over previous
//
#include <hip/hip_runtime.h>

#define SS 2048
#define DD 1024
#define HH 16
#define MM 4096
#define KK 1024

typedef __attribute__((ext_vector_type(8))) short bf16x8;
typedef __attribute__((ext_vector_type(4))) float f32x4;
typedef __attribute__((ext_vector_type(16))) float f32x16;
typedef __attribute__((ext_vector_type(4))) float float4_t;
typedef __attribute__((ext_vector_type(4))) short short4_t;

__device__ __forceinline__ short f2bf(float f) {
    union { float f; unsigned u; } x; x.f = f;
    unsigned r = x.u + 0x7fffu + ((x.u >> 16) & 1u);
    return (short)(r >> 16);
}

__device__ __forceinline__ f32x4 mfma16(bf16x8 a, bf16x8 b, f32x4 c) {
    return __builtin_amdgcn_mfma_f32_16x16x32_bf16(a, b, c, 0, 0, 0);
}
__device__ __forceinline__ f32x16 mfma32(bf16x8 a, bf16x8 b, f32x16 c) {
    return __builtin_amdgcn_mfma_f32_32x32x16_bf16(a, b, c, 0, 0, 0);
}

__device__ __forceinline__ void gl_lds16(const void* g, void* l) {
    __builtin_amdgcn_global_load_lds(
        (const __attribute__((address_space(1))) void*)g,
        (__attribute__((address_space(3))) void*)l, 16, 0, 0);
}

__device__ __forceinline__ float exp2a(float x) {
    float r; asm("v_exp_f32 %0, %1" : "=v"(r) : "v"(x)); return r;
}
__device__ __forceinline__ int cvtpk(float lo, float hi) {
    int r; asm("v_cvt_pk_bf16_f32 %0, %1, %2" : "=v"(r) : "v"(lo), "v"(hi)); return r;
}
__device__ __forceinline__ void pswap(int& a, int& b) {
    asm("v_permlane32_swap_b32 %0, %1" : "+v"(a), "+v"(b));
}

// ---------------- conversion passes: fp32 -> bf16 ----------------
__global__ __launch_bounds__(256)
void convX(const float* __restrict__ x0, const float* __restrict__ x1,
           const float* __restrict__ x2, short* __restrict__ dst) {
    const float* s = (blockIdx.y == 0) ? x0 : (blockIdx.y == 1) ? x1 : x2;
    const size_t i = ((size_t)blockIdx.x * 256 + threadIdx.x) * 8;
    float4_t a = *(const float4_t*)(s + i);
    float4_t b = *(const float4_t*)(s + i + 4);
    bf16x8 o;
#pragma unroll
    for (int e = 0; e < 4; ++e) { o[e] = f2bf(a[e]); o[4 + e] = f2bf(b[e]); }
    *(bf16x8*)(dst + (size_t)blockIdx.y * MM * KK + i) = o;
}

__global__ __launch_bounds__(256)
void convW(const float* __restrict__ w0, const float* __restrict__ w1,
           const float* __restrict__ w2, const float* __restrict__ w3,
           short* __restrict__ dst) {
    const float* s = (blockIdx.y == 0) ? w0 : (blockIdx.y == 1) ? w1
                   : (blockIdx.y == 2) ? w2 : w3;
    const size_t i = ((size_t)blockIdx.x * 256 + threadIdx.x) * 8;
    float4_t a = *(const float4_t*)(s + i);
    float4_t b = *(const float4_t*)(s + i + 4);
    bf16x8 o;
#pragma unroll
    for (int e = 0; e < 4; ++e) { o[e] = f2bf(a[e]); o[4 + e] = f2bf(b[e]); }
    *(bf16x8*)(dst + (size_t)blockIdx.y * KK * KK + i) = o;
}

// ---------------- m97-style bf16 GEMM core: C += A * W^T ----------------
__device__ __forceinline__ void gemm_loop(const short* __restrict__ A,
                                          const short* __restrict__ Bw,
                                          int m0, int n0,
                                          short* As, short* Bs,
                                          f32x4 acc[4][4]) {
    const int tid = threadIdx.x;
    const int lane = tid & 63, w = tid >> 6;
    const int wr = w >> 1, wc = w & 1;
    const int lr = lane & 15, lg = lane >> 4;

    const int c1 = tid + 256;
    const int r0 = tid >> 2, o0 = (tid & 3) * 8;
    const int r1 = c1 >> 2, o1 = (c1 & 3) * 8;
    const short* ga0 = A + (size_t)(m0 + r0) * KK + o0;
    const short* ga1 = A + (size_t)(m0 + r1) * KK + o1;
    const short* gb0 = Bw + (size_t)(n0 + r0) * KK + o0;
    const short* gb1 = Bw + (size_t)(n0 + r1) * KK + o1;
    char* lA = (char*)As + tid * 16;
    char* lB = (char*)Bs + tid * 16;

#define GSTAGE(buf, kofs)                                  \
    { gl_lds16(ga0 + (kofs), lA + (buf) * 8192);           \
      gl_lds16(ga1 + (kofs), lA + 4096 + (buf) * 8192);    \
      gl_lds16(gb0 + (kofs), lB + (buf) * 8192);           \
      gl_lds16(gb1 + (kofs), lB + 4096 + (buf) * 8192); }

    GSTAGE(0, 0);
    __syncthreads();
    int cur = 0;
    for (int kt = 0; kt < KK / 32; ++kt) {
        if (kt + 1 < KK / 32) GSTAGE(cur ^ 1, (kt + 1) * 32);
        const char* ba = (const char*)As + cur * 8192;
        const char* bb = (const char*)Bs + cur * 8192;
        bf16x8 af[4], bfr[4];
#pragma unroll
        for (int i = 0; i < 4; ++i) {
            af[i]  = *(const bf16x8*)(ba + (wr * 64 + i * 16 + lr) * 64 + lg * 16);
            bfr[i] = *(const bf16x8*)(bb + (wc * 64 + i * 16 + lr) * 64 + lg * 16);
        }
#pragma unroll
        for (int mi = 0; mi < 4; ++mi)
#pragma unroll
            for (int ni = 0; ni < 4; ++ni)
                acc[mi][ni] = mfma16(af[mi], bfr[ni], acc[mi][ni]);
        __syncthreads();
        cur ^= 1;
    }
#undef GSTAGE
}

// ---- QKV: z=0 -> Q (scaled by 0.125*log2e, head-major), z=1 -> K (head-major), z=2 -> V^T plain ----
__global__ __launch_bounds__(256, 2)
void qkv_gemm(const short* __restrict__ Xb, const short* __restrict__ Wb,
              const float* __restrict__ bq, const float* __restrict__ bk,
              const float* __restrict__ bv,
              short* __restrict__ Qo, short* __restrict__ Ko, short* __restrict__ Vto) {
    __shared__ __align__(16) short As[2 * 4096];
    __shared__ __align__(16) short Bs[2 * 4096];
    const int z = blockIdx.z;
    const short* A = Xb + (size_t)z * MM * KK;
    const short* W = Wb + (size_t)z * KK * KK;
    const float* bias = (z == 0) ? bq : (z == 1) ? bk : bv;
    const float scale = (z == 0) ? 0.125f * 1.44269504088896f : 1.0f;
    const int m0 = blockIdx.x * 128, n0 = blockIdx.y * 128;

    f32x4 zero = {0.f, 0.f, 0.f, 0.f};
    f32x4 acc[4][4];
#pragma unroll
    for (int i = 0; i < 4; ++i)
#pragma unroll
        for (int j = 0; j < 4; ++j) acc[i][j] = zero;

    gemm_loop(A, W, m0, n0, As, Bs, acc);

    const int tid = threadIdx.x;
    const int lane = tid & 63, w = tid >> 6;
    const int wr = w >> 1, wc = w & 1;
    const int lr = lane & 15, lg = lane >> 4;

#pragma unroll
    for (int mi = 0; mi < 4; ++mi) {
        const int mbase = m0 + wr * 64 + mi * 16 + lg * 4;
        const int b = mbase >> 11, s = mbase & 2047;
#pragma unroll
        for (int ni = 0; ni < 4; ++ni) {
            const int n = n0 + wc * 64 + ni * 16 + lr;
            const float bvv = bias[n];
            const int h = n >> 6, dk = n & 63;
            if (z == 2) {
                short4_t pk;
#pragma unroll
                for (int r = 0; r < 4; ++r) pk[r] = f2bf(acc[mi][ni][r] + bvv);
                *(short4_t*)(Vto + ((size_t)((b * HH + h) * 64 + dk) << 11) + s) = pk;
            } else {
                short* dst = (z == 0) ? Qo : Ko;
#pragma unroll
                for (int r = 0; r < 4; ++r)
                    dst[((size_t)((b * HH + h) * SS + (s + r)) << 6) + dk] =
                        f2bf((acc[mi][ni][r] + bvv) * scale);
            }
        }
    }
}

// ---- output projection: out = ctx * Wo^T + bo (fp32) ----
__global__ __launch_bounds__(256, 2)
void out_gemm(const short* __restrict__ ctx, const short* __restrict__ Wo,
              const float* __restrict__ bo, float* __restrict__ out) {
    __shared__ __align__(16) short As[2 * 4096];
    __shared__ __align__(16) short Bs[2 * 4096];
    const int m0 = blockIdx.x * 128, n0 = blockIdx.y * 128;

    f32x4 zero = {0.f, 0.f, 0.f, 0.f};
    f32x4 acc[4][4];
#pragma unroll
    for (int i = 0; i < 4; ++i)
#pragma unroll
        for (int j = 0; j < 4; ++j) acc[i][j] = zero;

    gemm_loop(ctx, Wo, m0, n0, As, Bs, acc);

    const int tid = threadIdx.x;
    const int lane = tid & 63, w = tid >> 6;
    const int wr = w >> 1, wc = w & 1;
    const int lr = lane & 15, lg = lane >> 4;

#pragma unroll
    for (int mi = 0; mi < 4; ++mi)
#pragma unroll
        for (int ni = 0; ni < 4; ++ni) {
            const int n = n0 + wc * 64 + ni * 16 + lr;
            const float bvv = bo[n];
#pragma unroll
            for (int r = 0; r < 4; ++r) {
                const int m = m0 + wr * 64 + mi * 16 + lg * 4 + r;
                out[(size_t)m * KK + n] = acc[mi][ni][r] + bvv;
            }
        }
}

// ---- flash attention, 32x32 MFMA, swapped QK^T, fragment-order LDS ----
// Q,K head-major bf16 (Q pre-scaled into log2 domain); Vt[b][h][d][s] plain bf16; ctx bf16 [B][S][D]
__global__ __launch_bounds__(256, 2)
void attn_kernel(const short* __restrict__ Qg, const short* __restrict__ Kg,
                 const short* __restrict__ Vtg, const int* __restrict__ mask,
                 short* __restrict__ ctxb) {
    __shared__ __align__(16) short Ks[2][4096];  // fragment-order: chunk (kb*4+t)*64+lane
    __shared__ __align__(16) short Vs[2][4096];  // fragment-order: chunk (db*4+kk)*64+lane

    const int tid = threadIdx.x, w = tid >> 6, lane = tid & 63;
    const int l31 = lane & 31, hi = lane >> 5;
    const int bh = blockIdx.y, b = bh >> 4, h = bh & 15;
    const int q0w = blockIdx.x * 128 + w * 32;  // this wave's 32 q-rows

    const short* Qh = Qg + (size_t)bh * SS * 64;
    const short* Kh = Kg + (size_t)bh * SS * 64;
    const short* Vh = Vtg + (size_t)bh * 64 * SS;
    const int* mrow = mask + b * SS;

    // Q B-fragments: qf[t] = Q[q0w+l31][t*16 + hi*8 .. +7]
    bf16x8 qf[4];
#pragma unroll
    for (int t = 0; t < 4; ++t)
        qf[t] = *(const bf16x8*)(Qh + (q0w + l31) * 64 + t * 16 + hi * 8);

    f32x16 octx0, octx1;
#pragma unroll
    for (int r = 0; r < 16; ++r) { octx0[r] = 0.f; octx1[r] = 0.f; }
    float mrun = -1e30f, lrun = 0.f;  // for q = q0w + l31

    // staging pointers (thread handles chunks tid and tid+256 of each of K,V)
    const int tq = (tid >> 6) & 3;
    const short* gk0 = Kh + (l31) * 64 + tq * 16 + hi * 8;          // kb=0
    const short* gk1 = Kh + (32 + l31) * 64 + tq * 16 + hi * 8;     // kb=1
    const short* gv0 = Vh + (size_t)(l31) * SS + tq * 16 + hi * 8;      // db=0
    const short* gv1 = Vh + (size_t)(32 + l31) * SS + tq * 16 + hi * 8; // db=1
    char* lK = (char*)Ks + tid * 16;
    char* lV = (char*)Vs + tid * 16;

#define ASTAGE(buf, key0)                                      \
    { gl_lds16(gk0 + (key0) * 64, lK + (buf) * 8192);          \
      gl_lds16(gk1 + (key0) * 64, lK + 4096 + (buf) * 8192);   \
      gl_lds16(gv0 + (key0), lV + (buf) * 8192);               \
      gl_lds16(gv1 + (key0), lV + 4096 + (buf) * 8192); }

    ASTAGE(0, 0);
    __syncthreads();
    int cur = 0;

    for (int it = 0; it < SS / 64; ++it) {
        const int key0 = it * 64;
        if (it + 1 < SS / 64) ASTAGE(cur ^ 1, key0 + 64);

        const char* cK = (const char*)Ks + cur * 8192;
        const char* cV = (const char*)Vs + cur * 8192;

        // QK^T: S^T tiles, D col = q (lane&31), rows = keys via crow(r,hi)
        f32x16 s0, s1;
#pragma unroll
        for (int r = 0; r < 16; ++r) { s0[r] = 0.f; s1[r] = 0.f; }
#pragma unroll
        for (int t = 0; t < 4; ++t) {
            bf16x8 a0 = *(const bf16x8*)(cK + ((0 * 4 + t) * 64 + lane) * 16);
            bf16x8 a1 = *(const bf16x8*)(cK + ((1 * 4 + t) * 64 + lane) * 16);
            s0 = mfma32(a0, qf[t], s0);
            s1 = mfma32(a1, qf[t], s1);
        }

        // mask (key-wise); fast path when tile fully unmasked
        const int mk = mrow[key0 + lane];
        if (!__all(mk != 0)) {
#pragma unroll
            for (int r = 0; r < 16; ++r) {
                const int kl = (r & 3) + 8 * (r >> 2) + 4 * hi;
                if (mrow[key0 + kl] == 0) s0[r] = -1e9f;
                if (mrow[key0 + 32 + kl] == 0) s1[r] = -1e9f;
            }
        }

        // tile max (tree) for q = l31
        float tv[16];
#pragma unroll
        for (int r = 0; r < 16; ++r) tv[r] = fmaxf(s0[r], s1[r]);
#pragma unroll
        for (int off = 8; off >= 1; off >>= 1)
#pragma unroll
            for (int r = 0; r < 8; ++r)
                if (r < off) tv[r] = fmaxf(tv[r], tv[r + off]);
        float tm = tv[0];
        tm = fmaxf(tm, __shfl_xor(tm, 32));

        // defer-max: rescale only when tile max exceeds running max + 8 (log2 units)
        if (!__all(tm <= mrun + 8.0f)) {
            const float mnew = fmaxf(mrun, tm);
            const float alpha = exp2a(mrun - mnew);
            lrun *= alpha;
#pragma unroll
            for (int r = 0; r < 16; ++r) {
                const int ql = (r & 3) + 8 * (r >> 2) + 4 * hi;
                const float aq = __shfl(alpha, ql);
                octx0[r] *= aq;
                octx1[r] *= aq;
            }
            mrun = mnew;
        }

        // p = exp2(s - mrun); row-sum (tree)
#pragma unroll
        for (int r = 0; r < 16; ++r) {
            s0[r] = exp2a(s0[r] - mrun);
            s1[r] = exp2a(s1[r] - mrun);
        }
        float sv[16];
#pragma unroll
        for (int r = 0; r < 16; ++r) sv[r] = s0[r] + s1[r];
#pragma unroll
        for (int off = 8; off >= 1; off >>= 1)
#pragma unroll
            for (int r = 0; r < 8; ++r)
                if (r < off) sv[r] += sv[r + off];
        float rs = sv[0];
        rs += __shfl_xor(rs, 32);
        lrun += rs;

        // pack P into 4 A-fragments (16 keys each) via cvt_pk + permlane32_swap
        bf16x8 pa[4];
#pragma unroll
        for (int kb = 0; kb < 2; ++kb) {
            const f32x16& sv16 = kb ? s1 : s0;
#pragma unroll
            for (int half = 0; half < 2; ++half) {
                const int base = half * 8;
                int A  = cvtpk(sv16[base + 0], sv16[base + 1]);
                int Bw = cvtpk(sv16[base + 2], sv16[base + 3]);
                int Cw = cvtpk(sv16[base + 4], sv16[base + 5]);
                int Dw = cvtpk(sv16[base + 6], sv16[base + 7]);
                pswap(A, Cw);
                pswap(Bw, Dw);
                union { int wv[4]; bf16x8 v; } u;
                u.wv[0] = A; u.wv[1] = Bw; u.wv[2] = Cw; u.wv[3] = Dw;
                pa[kb * 2 + half] = u.v;
            }
        }

        // PV: octx[q][d], A = P, B = V^T fragments
#pragma unroll
        for (int kk = 0; kk < 4; ++kk) {
            bf16x8 v0 = *(const bf16x8*)(cV + ((0 * 4 + kk) * 64 + lane) * 16);
            bf16x8 v1 = *(const bf16x8*)(cV + ((1 * 4 + kk) * 64 + lane) * 16);
            octx0 = mfma32(pa[kk], v0, octx0);
            octx1 = mfma32(pa[kk], v1, octx1);
        }

        __syncthreads();
        cur ^= 1;
    }
#undef ASTAGE

    // epilogue: ctx[b][q0w + crow(r,hi)][h*64 + db*32 + l31]
    const float linv = 1.f / lrun;
#pragma unroll
    for (int r = 0; r < 16; ++r) {
        const int ql = (r & 3) + 8 * (r >> 2) + 4 * hi;
        const float li = __shfl(linv, ql);
        short* orow = ctxb + (size_t)(b * SS + q0w + ql) * DD + h * 64 + l31;
        orow[0]  = f2bf(octx0[r] * li);
        orow[32] = f2bf(octx1[r] * li);
    }
}

extern "C" void kernel_launch(void* const* d_in, const int* in_sizes, int n_in,
                              void* d_out, int out_size, void* d_ws, size_t ws_size,
                              hipStream_t stream) {
    const float* preQ = (const float*)d_in[0];
    const float* preK = (const float*)d_in[1];
    const float* preV = (const float*)d_in[2];
    const float* Wq   = (const float*)d_in[3];
    const float* bq   = (const float*)d_in[4];
    const float* Wk   = (const float*)d_in[5];
    const float* bk   = (const float*)d_in[6];
    const float* Wv   = (const float*)d_in[7];
    const float* bv   = (const float*)d_in[8];
    const float* Wo   = (const float*)d_in[9];
    const float* bo   = (const float*)d_in[10];
    const int*   mask = (const int*)d_in[11];
    float* out = (float*)d_out;

    char* ws = (char*)d_ws;
    short* Xb  = (short*)(ws);                           // 24 MB
    short* Wb  = (short*)(ws + (size_t)25165824);        // 8 MB
    short* Qw  = (short*)(ws + (size_t)33554432);        // 8 MB
    short* Kw  = (short*)(ws + (size_t)41943040);        // 8 MB
    short* Vtw = (short*)(ws + (size_t)50331648);        // 8 MB
    short* Ctx = (short*)(ws + (size_t)58720256);        // 8 MB

    convX<<<dim3(2048, 3), 256, 0, stream>>>(preQ, preK, preV, Xb);
    convW<<<dim3(512, 4), 256, 0, stream>>>(Wq, Wk, Wv, Wo, Wb);
    qkv_gemm<<<dim3(32, 8, 3), 256, 0, stream>>>(Xb, Wb, bq, bk, bv, Qw, Kw, Vtw);
    attn_kernel<<<dim3(16, 32), 256, 0, stream>>>(Qw, Kw, Vtw, mask, Ctx);
    out_gemm<<<dim3(32, 8), 256, 0, stream>>>(Ctx, Wb + (size_t)3 * KK * KK, bo, out);
}